// Round 2
// baseline (159.191 us; speedup 1.0000x reference)
//
#include <hip/hip_runtime.h>
#include <hip/hip_cooperative_groups.h>

namespace cg = cooperative_groups;

// Problem constants
#define LSEQ 256   // sequence length (i, j range)
#define INC  256   // in_channels
#define HID  32    // hidden_dim
#define OUTC 32    // out_channels
#define DE   1024  // HID*HID (LayerNorm width)
#define EPSV 1e-5f

// aPad layout: row i of a stored at aPad[(i>>3)*ASTR + d*8 + (i&7)]
// ASTR=264: GEMM-phase float4 reads across iT lanes are at worst 2-way
// bank-aliased (free per m136); staging scatter 2-way. 264*4B is 16B-aligned.
#define ASTR 264
// tPad/red layout stride 36: 36%32==4 -> float4 reads/writes across lanes hit
// all 32 banks (conflict-free), 144 B keeps float4 alignment.
#define TSTR 36

// ---------------------------------------------------------------------------
// Single cooperative kernel, grid 256 (block j), 256 threads. NO workspace:
// a/S/Q are stashed in the head of `out` (34 KB) between grid syncs, then
// overwritten by phase C.
//   Phase A: a[j,:] = x[j,:]@W1 + b1 ; S_j, Q_j ; T_j[d][o] (in LDS only),
//            GW[o], C[o] fused into the same W2-read loop (W2 read once/block)
//   grid.sync
//   Phase B: load full a (chunk-transposed), S, Q stash into LDS
//   grid.sync   (all stash reads complete before any final write)
//   Phase C: thread (iT=t>>3, oT=t&7) owns 8i x 4o:
//            out[i,j,o] = r_ij*(sum_d a[i,d]*T_j[d,o] - mu_ij*GW[o]) + C[o]
// ---------------------------------------------------------------------------
__global__ __launch_bounds__(256) void fused_opm(
    const float* __restrict__ x, const float* __restrict__ W1, const float* __restrict__ b1,
    const float* __restrict__ gamma, const float* __restrict__ beta,
    const float* __restrict__ W2, const float* __restrict__ b2,
    float* out)
{
    const int j = blockIdx.x;
    const int t = threadIdx.x;

    __shared__ float xL[INC];            // 1 KB
    __shared__ float sh[256];            // 1 KB
    __shared__ float aL[HID];            // 128 B
    __shared__ float tPad[HID * TSTR];   // 4.6 KB  (T_j)
    __shared__ float redG[HID * TSTR];   // 4.6 KB  (GW partials)
    __shared__ float redB[HID * TSTR];   // 4.6 KB  (C partials)
    __shared__ float gwL[OUTC], cL[OUTC];
    __shared__ float aPad[32 * ASTR];    // 33.8 KB
    __shared__ float sL[LSEQ];           // 1 KB
    __shared__ float qL[LSEQ];           // 1 KB

    // stash region: first 8704 floats of out (i=0 row + head of i=1 row),
    // fully rewritten by phase C after grid.sync #2.
    float* stash_a = out;            // [256*32]
    float* stash_S = out + 8192;     // [256]
    float* stash_Q = out + 8448;     // [256]

    // ================= Phase A =================
    xL[t] = x[j * INC + t];
    __syncthreads();

    {   // a[j,d]: thread (kc = t>>5 owns 32-k chunk, d = t&31)
        const int d = t & 31, kc = t >> 5;
        const float* w = W1 + (kc * 32) * HID + d;   // coalesced over d
        float p0 = 0.f, p1 = 0.f;                    // 2 independent chains
        #pragma unroll
        for (int k = 0; k < 16; ++k) {
            p0 = fmaf(xL[kc * 32 + 2 * k],     w[(2 * k) * HID],     p0);
            p1 = fmaf(xL[kc * 32 + 2 * k + 1], w[(2 * k + 1) * HID], p1);
        }
        sh[t] = p0 + p1;
    }
    __syncthreads();

    if (t < 32) {
        float tot = b1[t];
        #pragma unroll
        for (int c = 0; c < 8; ++c) tot += sh[c * 32 + t];
        aL[t] = tot;
        stash_a[j * HID + t] = tot;
        // S_j, Q_j via 32-lane butterfly
        float s = tot, q = tot * tot;
        #pragma unroll
        for (int off = 16; off > 0; off >>= 1) {
            s += __shfl_xor(s, off);
            q += __shfl_xor(q, off);
        }
        if (t == 0) { stash_S[j] = s; stash_Q[j] = q; }
    }
    __syncthreads();

    {   // T_j + GW + C fused: one pass over gamma/beta/W2.
        // thread (dd = t>>3, o4 = (t&7)*4); W2 float4 reads coalesced over o.
        const int dd = t >> 3, o4 = (t & 7) * 4;
        float4 tAcc = {0.f, 0.f, 0.f, 0.f};
        float4 gAcc = {0.f, 0.f, 0.f, 0.f};
        float4 bAcc = {0.f, 0.f, 0.f, 0.f};
        #pragma unroll
        for (int e = 0; e < 32; ++e) {
            const int de = dd * 32 + e;
            const float g  = gamma[de];
            const float bb = beta[de];
            const float ga = g * aL[e];
            const float4 w4 = *(const float4*)(W2 + de * OUTC + o4);
            tAcc.x = fmaf(ga, w4.x, tAcc.x);
            tAcc.y = fmaf(ga, w4.y, tAcc.y);
            tAcc.z = fmaf(ga, w4.z, tAcc.z);
            tAcc.w = fmaf(ga, w4.w, tAcc.w);
            gAcc.x = fmaf(g,  w4.x, gAcc.x);
            gAcc.y = fmaf(g,  w4.y, gAcc.y);
            gAcc.z = fmaf(g,  w4.z, gAcc.z);
            gAcc.w = fmaf(g,  w4.w, gAcc.w);
            bAcc.x = fmaf(bb, w4.x, bAcc.x);
            bAcc.y = fmaf(bb, w4.y, bAcc.y);
            bAcc.z = fmaf(bb, w4.z, bAcc.z);
            bAcc.w = fmaf(bb, w4.w, bAcc.w);
        }
        *(float4*)(tPad + dd * TSTR + o4) = tAcc;
        *(float4*)(redG + dd * TSTR + o4) = gAcc;
        *(float4*)(redB + dd * TSTR + o4) = bAcc;
    }
    __syncthreads();

    if (t < 32) {   // reduce GW/C over dd; lanes read consecutive -> no conflict
        float g = 0.f, bb = 0.f;
        #pragma unroll
        for (int dd = 0; dd < 32; ++dd) {
            g  += redG[dd * TSTR + t];
            bb += redB[dd * TSTR + t];
        }
        gwL[t] = g;
        cL[t]  = bb + b2[t];
    }

    __threadfence();            // device-scope release of the stash
    cg::this_grid().sync();

    // ================= Phase B =================
    {   // thread t owns row i=t of a: 8 float4 L2-hot reads, scatter to aPad
        const float4* ar4 = (const float4*)(stash_a + t * HID);
        const int base = (t >> 3) * ASTR + (t & 7);
        #pragma unroll
        for (int c = 0; c < 8; ++c) {
            const float4 v = ar4[c];
            const int d = c * 4;
            aPad[base + (d + 0) * 8] = v.x;
            aPad[base + (d + 1) * 8] = v.y;
            aPad[base + (d + 2) * 8] = v.z;
            aPad[base + (d + 3) * 8] = v.w;
        }
        sL[t] = stash_S[t];
        qL[t] = stash_Q[t];
    }
    cg::this_grid().sync();     // all stash reads done before any final write

    // ================= Phase C =================
    const int iT = t >> 3, oT = t & 7;
    const int abase = iT * ASTR;
    float acc[8][4];
    #pragma unroll
    for (int m = 0; m < 8; ++m)
        #pragma unroll
        for (int k = 0; k < 4; ++k) acc[m][k] = 0.f;

    #pragma unroll
    for (int d = 0; d < 32; ++d) {
        const float4 a0 = *(const float4*)(aPad + abase + d * 8);
        const float4 a1 = *(const float4*)(aPad + abase + d * 8 + 4);
        const float4 tf = *(const float4*)(tPad + d * TSTR + oT * 4);
        const float am[8] = {a0.x, a0.y, a0.z, a0.w, a1.x, a1.y, a1.z, a1.w};
        const float tk[4] = {tf.x, tf.y, tf.z, tf.w};
        #pragma unroll
        for (int m = 0; m < 8; ++m)
            #pragma unroll
            for (int k = 0; k < 4; ++k)
                acc[m][k] = fmaf(am[m], tk[k], acc[m][k]);
    }

    const float Sj = sL[j], Qj = qL[j];
    const float gw0 = gwL[oT * 4 + 0], gw1 = gwL[oT * 4 + 1];
    const float gw2 = gwL[oT * 4 + 2], gw3 = gwL[oT * 4 + 3];
    const float c0 = cL[oT * 4 + 0], c1 = cL[oT * 4 + 1];
    const float c2 = cL[oT * 4 + 2], c3 = cL[oT * 4 + 3];

    #pragma unroll
    for (int m = 0; m < 8; ++m) {
        const int i = iT * 8 + m;
        const float Si = sL[i], Qi = qL[i];
        const float mu  = Si * Sj * (1.0f / 1024.0f);
        const float ex2 = Qi * Qj * (1.0f / 1024.0f);
        const float var = ex2 - mu * mu;
        const float r   = rsqrtf(var + EPSV);
        float4 o4v;
        o4v.x = fmaf(r, acc[m][0] - mu * gw0, c0);
        o4v.y = fmaf(r, acc[m][1] - mu * gw1, c1);
        o4v.z = fmaf(r, acc[m][2] - mu * gw2, c2);
        o4v.w = fmaf(r, acc[m][3] - mu * gw3, c3);
        // 8 consecutive lanes (oT=0..7) cover one full 128 B row (i,j,:)
        *(float4*)(out + (i * LSEQ + j) * OUTC + oT * 4) = o4v;
    }
}

// ---------------------------------------------------------------------------
extern "C" void kernel_launch(void* const* d_in, const int* in_sizes, int n_in,
                              void* d_out, int out_size, void* d_ws, size_t ws_size,
                              hipStream_t stream)
{
    const float* x     = (const float*)d_in[0];
    const float* W1    = (const float*)d_in[1];
    const float* b1    = (const float*)d_in[2];
    const float* gamma = (const float*)d_in[3];
    const float* beta  = (const float*)d_in[4];
    const float* W2    = (const float*)d_in[5];
    const float* b2    = (const float*)d_in[6];
    float* out = (float*)d_out;
    (void)d_ws; (void)ws_size;   // workspace intentionally unused

    void* args[] = {(void*)&x, (void*)&W1, (void*)&b1, (void*)&gamma,
                    (void*)&beta, (void*)&W2, (void*)&b2, (void*)&out};
    hipLaunchCooperativeKernel((const void*)fused_opm,
                               dim3(LSEQ), dim3(256), args, 0, stream);
}

// Round 3
// 77.303 us; speedup vs baseline: 2.0593x; 2.0593x over previous
//
#include <hip/hip_runtime.h>

// Problem constants
#define LSEQ 256   // sequence length (i, j range)
#define INC  256   // in_channels
#define HID  32    // hidden_dim
#define OUTC 32    // out_channels
#define DE   1024  // HID*HID (LayerNorm width)
#define EPSV 1e-5f

// aPad layout (k2): local row lr of a stored at aPad[(lr>>3)*ASTR + d*8 + (lr&7)]
// ASTR=264: 264%32==8, so GEMM-phase float4 reads (iT groups at chunk*264 + sub*4)
// hit 8 distinct 4-bank spans covering all 32 banks -> conflict-free; staging
// scalar scatter is 2-way (free per m136). 264*4B is 16B-aligned.
#define ASTR 264
// tPad layout: T[d][o] at tPad[d*TSTR + o]; 36%32==4 -> reads conflict-free,
// 36*4=144 B keeps float4 alignment.
#define TSTR 36

// ---------------------------------------------------------------------------
// k1: blocks 0..255 -> block j computes a[j,:], S_j, Q_j, and the fused
//     per-j projection matrix T_j[d][o] = sum_e a[j,e]*gamma[d*32+e]*W2[de,o].
//     block 256     -> GW[o]=sum_de gamma*W2 ; C[o]=sum_de beta*W2 + b2[o]
// Removes W2+gamma entirely from k2 and fills all 256 CUs.
// NOTE (round-2 post-mortem): do NOT fuse k1+k2 via cooperative grid.sync —
// measured ~40 µs per grid barrier on this stack (fused_opm 82 µs @ 2% VALU).
// Two small launches are ~3 µs total; the barrier alone costs 25x that.
// ---------------------------------------------------------------------------
__global__ __launch_bounds__(256) void k1_aT(
    const float* __restrict__ x, const float* __restrict__ W1, const float* __restrict__ b1,
    const float* __restrict__ gamma, const float* __restrict__ beta,
    const float* __restrict__ W2, const float* __restrict__ b2,
    float* __restrict__ a, float* __restrict__ S, float* __restrict__ Q,
    float* __restrict__ T, float* __restrict__ GW, float* __restrict__ C)
{
    __shared__ float sh[256];
    __shared__ float sh2[256];
    __shared__ float xL[256];
    __shared__ float aL[32];
    const int t = threadIdx.x;
    const int b = blockIdx.x;

    if (b < 256) {
        const int j = b;
        // ---- stage x row (coalesced) ----
        xL[t] = x[j * INC + t];
        __syncthreads();

        // ---- a[j,d] = x[j,:] @ W1[:,d] + b1[d] ----
        // thread (kc = t>>5 owns k-chunk of 32, d = t&31)
        const int d = t & 31, kc = t >> 5;
        const float* w = W1 + (kc * 32) * HID + d;   // coalesced over d
        float p0 = 0.f, p1 = 0.f;                    // 2 independent chains
        #pragma unroll
        for (int k = 0; k < 16; ++k) {
            p0 = fmaf(xL[kc * 32 + 2 * k],     w[(2 * k) * HID],     p0);
            p1 = fmaf(xL[kc * 32 + 2 * k + 1], w[(2 * k + 1) * HID], p1);
        }
        sh[t] = p0 + p1;
        __syncthreads();

        if (t < 32) {
            float tot = b1[t];
            #pragma unroll
            for (int c = 0; c < 8; ++c) tot += sh[c * 32 + t];
            aL[t] = tot;
            a[j * HID + t] = tot;
            // S_j, Q_j via 32-lane butterfly (offsets stay within lanes 0..31)
            float s = tot, q = tot * tot;
            #pragma unroll
            for (int off = 16; off > 0; off >>= 1) {
                s += __shfl_xor(s, off);
                q += __shfl_xor(q, off);
            }
            if (t == 0) { S[j] = s; Q[j] = q; }
        }
        __syncthreads();

        // ---- T_j[d][o] = sum_e aL[e]*gamma[d*32+e]*W2[(d*32+e)*32+o] ----
        // thread (dd = t>>3, o4 = (t&7)*4); W2 float4 reads coalesced over o.
        const int dd = t >> 3, o4 = (t & 7) * 4;
        float4 acc = {0.f, 0.f, 0.f, 0.f};
        #pragma unroll
        for (int e = 0; e < 32; ++e) {
            const float g = gamma[dd * 32 + e] * aL[e];
            const float4 wv = *(const float4*)(W2 + (dd * 32 + e) * OUTC + o4);
            acc.x = fmaf(g, wv.x, acc.x);
            acc.y = fmaf(g, wv.y, acc.y);
            acc.z = fmaf(g, wv.z, acc.z);
            acc.w = fmaf(g, wv.w, acc.w);
        }
        *(float4*)(T + j * DE + dd * 32 + o4) = acc;
    } else {
        // ---- constants: per-o sums over the 1024 LayerNorm lanes ----
        const int o = t & 31, chunk = t >> 5;     // 8 chunks x 128 de each
        float gw = 0.f, bw = 0.f;
        for (int k = 0; k < 128; ++k) {
            const int de = chunk * 128 + k;
            const float w = W2[de * OUTC + o];    // coalesced over o
            gw = fmaf(gamma[de], w, gw);
            bw = fmaf(beta[de],  w, bw);
        }
        sh[t] = gw; sh2[t] = bw;
        __syncthreads();
        if (t < 32) {
            float g = 0.f, bb = 0.f;
            #pragma unroll
            for (int c2 = 0; c2 < 8; ++c2) { g += sh[c2 * 32 + t]; bb += sh2[c2 * 32 + t]; }
            GW[t] = g;
            C[t]  = bb + b2[t];
        }
    }
}

// ---------------------------------------------------------------------------
// k2: pure staged GEMM + LN epilogue. Grid 512: j = bid&255, half = bid>>8
// (half in the high bit so both halves of a j land on the same XCD -> T_j
// is pulled into that L2 once). 2 blocks/CU = 8 waves/CU for latency hiding.
//   stage: aPad (128 i-rows, chunk-transposed), tPad (T_j), S, Q, GW, C
//   ONE __syncthreads, then:
//   thread (iT = t>>3, oT = t&7) owns 4i x 4o:
//     out[i,j,o] = r_ij*(sum_d a[i,d]*T_j[d,o] - mu_ij*GW[o]) + C[o]
// ---------------------------------------------------------------------------
__global__ __launch_bounds__(256) void k2_gemm(
    const float* __restrict__ a, const float* __restrict__ S, const float* __restrict__ Q,
    const float* __restrict__ GW, const float* __restrict__ C,
    const float* __restrict__ T, float* __restrict__ out)
{
    const int bid = blockIdx.x;
    const int j = bid & 255, half = bid >> 8;
    const int t = threadIdx.x;
    __shared__ float aPad[16 * ASTR];   // 16.9 KB (128 rows)
    __shared__ float tPad[32 * TSTR];   // 4.6 KB
    __shared__ float sL[LSEQ];
    __shared__ float qL[LSEQ];
    __shared__ float gwL[OUTC], cL[OUTC];

    // ---- stage a half: 2 threads per row, 4 float4 global reads each ----
    {
        const int r = t >> 1, p = t & 1;
        const float4* ar4 = (const float4*)(a + (half * 128 + r) * HID + p * 16);
        const int base = (r >> 3) * ASTR + (r & 7);
        #pragma unroll
        for (int c = 0; c < 4; ++c) {
            const float4 v = ar4[c];
            const int dd = p * 16 + c * 4;
            aPad[base + (dd + 0) * 8] = v.x;
            aPad[base + (dd + 1) * 8] = v.y;
            aPad[base + (dd + 2) * 8] = v.z;
            aPad[base + (dd + 3) * 8] = v.w;
        }
    }
    // ---- stage T_j: fully coalesced, 16 B/lane ----
    {
        const float4 v = *(const float4*)(T + j * DE + t * 4);
        const int dd = t >> 3, o4 = (t & 7) * 4;
        *(float4*)(tPad + dd * TSTR + o4) = v;
    }
    sL[t] = S[t];
    qL[t] = Q[t];
    if (t < OUTC) { gwL[t] = GW[t]; cL[t] = C[t]; }
    __syncthreads();

    // ---- reg-tiled GEMM: 4i x 4o per thread ----
    const int iT = t >> 3, oT = t & 7;
    const int abase = (iT >> 1) * ASTR + (iT & 1) * 4;  // chunk*ASTR + sub
    float acc[4][4];
    #pragma unroll
    for (int m = 0; m < 4; ++m)
        #pragma unroll
        for (int k = 0; k < 4; ++k) acc[m][k] = 0.f;

    #pragma unroll
    for (int d = 0; d < 32; ++d) {
        const float4 av = *(const float4*)(aPad + abase + d * 8);
        const float4 tv = *(const float4*)(tPad + d * TSTR + oT * 4);
        const float am[4] = {av.x, av.y, av.z, av.w};
        const float tk[4] = {tv.x, tv.y, tv.z, tv.w};
        #pragma unroll
        for (int m = 0; m < 4; ++m)
            #pragma unroll
            for (int k = 0; k < 4; ++k)
                acc[m][k] = fmaf(am[m], tk[k], acc[m][k]);
    }

    // ---- LN epilogue + store ----
    const float Sj = sL[j], Qj = qL[j];
    const float gw0 = gwL[oT * 4 + 0], gw1 = gwL[oT * 4 + 1];
    const float gw2 = gwL[oT * 4 + 2], gw3 = gwL[oT * 4 + 3];
    const float c0 = cL[oT * 4 + 0], c1 = cL[oT * 4 + 1];
    const float c2 = cL[oT * 4 + 2], c3 = cL[oT * 4 + 3];

    #pragma unroll
    for (int m = 0; m < 4; ++m) {
        const int lr = (iT >> 1) * 8 + (iT & 1) * 4 + m;  // local row
        const int i = half * 128 + lr;
        const float Si = sL[i], Qi = qL[i];
        const float mu  = Si * Sj * (1.0f / 1024.0f);
        const float ex2 = Qi * Qj * (1.0f / 1024.0f);
        const float var = ex2 - mu * mu;
        const float r   = rsqrtf(var + EPSV);
        float4 o4v;
        o4v.x = fmaf(r, acc[m][0] - mu * gw0, c0);
        o4v.y = fmaf(r, acc[m][1] - mu * gw1, c1);
        o4v.z = fmaf(r, acc[m][2] - mu * gw2, c2);
        o4v.w = fmaf(r, acc[m][3] - mu * gw3, c3);
        // 8 consecutive lanes (oT=0..7) cover one full 128 B row (i,j,:)
        *(float4*)(out + (i * LSEQ + j) * OUTC + oT * 4) = o4v;
    }
}

// ---------------------------------------------------------------------------
extern "C" void kernel_launch(void* const* d_in, const int* in_sizes, int n_in,
                              void* d_out, int out_size, void* d_ws, size_t ws_size,
                              hipStream_t stream)
{
    const float* x     = (const float*)d_in[0];
    const float* W1    = (const float*)d_in[1];
    const float* b1    = (const float*)d_in[2];
    const float* gamma = (const float*)d_in[3];
    const float* beta  = (const float*)d_in[4];
    const float* W2    = (const float*)d_in[5];
    const float* b2    = (const float*)d_in[6];
    float* out = (float*)d_out;

    // workspace layout (floats)
    float* ws = (float*)d_ws;
    float* a  = ws;            // 8192
    float* S  = ws + 8192;     // 256
    float* Q  = ws + 8448;     // 256
    float* GW = ws + 8704;     // 32
    float* C  = ws + 8736;     // 32
    float* T  = ws + 8768;     // 256*1024 = 262144

    k1_aT<<<257, 256, 0, stream>>>(x, W1, b1, gamma, beta, W2, b2, a, S, Q, T, GW, C);
    k2_gemm<<<512, 256, 0, stream>>>(a, S, Q, GW, C, T, out);
}